// Round 1
// baseline (27543.536 us; speedup 1.0000x reference)
//
#include <hip/hip_runtime.h>
#include <cmath>

constexpr int kB = 64, kS = 512, kD = 128, kH = 512, kOut = 24;
constexpr int kBlocks = 256, kThreads = 512;   // grid<=256: proven coop-launchable
constexpr size_t kBarOffBytes = (size_t)5 * kB * kH * 4;   // after H0,H1,tmp1

struct Params {
  const float* x;
  const float* w0[4]; const float* b0[4];   // f,i,o,g  [512,640] / [512]
  const float* w1[4]; const float* b1[4];   // f,i,o,g  [512,1024] / [512]
  const float* fc1w; const float* fc1b;
  const float* fc2w; const float* fc2b;
  float* H0;    // 2 buffers [64][512]
  float* H1;    // 2 buffers [64][512]
  float* tmp1;  // [64][512]
  unsigned* bar; // barrier state: leaf[8] @ i*16, root @ 128, gen @ 144
  float* out;   // [64][24]
};

__device__ __forceinline__ float sigmoidf_(float v) {
  return 1.0f / (1.0f + expf(-v));
}

// Two-level monotone barrier. Leaf = bid&7 (one per XCD under round-robin
// dispatch; perf-only assumption). 32 blocks/leaf, 8 leaves -> root -> gen.
__device__ __forceinline__ void grid_barrier(unsigned* bar, int bid, unsigned r) {
  __syncthreads();
  if (threadIdx.x == 0) {
    __threadfence();                                  // release
    unsigned prev = atomicAdd(&bar[(bid & 7) * 16], 1u);
    if (prev == r * 32u + 31u) {                      // leaf winner
      __threadfence();
      unsigned rp = atomicAdd(&bar[128], 1u);
      if (rp == r * 8u + 7u) {                        // root winner
        __threadfence();
        atomicAdd(&bar[144], 1u);                     // gen = r+1
      }
    }
    while (__hip_atomic_load(&bar[144], __ATOMIC_RELAXED,
                             __HIP_MEMORY_SCOPE_AGENT) <= r) {
      __builtin_amdgcn_s_sleep(2);
    }
    __threadfence();                                  // acquire
  }
  __syncthreads();
}

// Block (cgi, bh): cgi=bid&127 owns hidden cols j0=4*cgi..j0+3 (all 4 gates),
// bh=bid>>7 owns batches bh*32..+31.  bid and bid+128 share a weight slice
// AND land on the same XCD (128 % 8 == 0) -> per-XCD weight footprint 1.66MB,
// L2-resident.
// Thread tid = r4*128 + kt*8 + bg  (r4: gate, kt: k-split, bg: batch group).
__global__ void __launch_bounds__(kThreads, 4)
lstm_persistent(Params p) {
  __shared__ float ustg[2][32 * 132];  // double-buffered u-stage (2 x 16.5KB)
  __shared__ float part[16 * 520];     // k-split partials
  __shared__ float gs[512];            // gate preactivations [row(16)][b(32)]

  const int tid = threadIdx.x;
  const int bid = blockIdx.x;
  const int cgi = bid & 127;
  const int bh  = bid >> 7;
  const int j0  = cgi * 4;
  const int bbase = bh * 32;

  const int r4 = tid >> 7;
  const int kt = (tid >> 3) & 15;
  const int bg = tid & 7;

  // staging thread map: thread loads float4 k4s of batch rows bbs0 and bbs1
  const int k4s  = tid & 31;
  const int bbs0 = tid >> 5;
  const int bbs1 = bbs0 + 16;
  const int bL0 = bbase + bbs0, bL1 = bbase + bbs1;

  unsigned rnd = 0;

  // zero-init buffers read at t=0 (buffer index 1)
  if (tid < 128) {
    const int jl = tid >> 5, bb = tid & 31;
    const int b = bbase + bb;
    p.H0[kB * kH + b * kH + j0 + jl] = 0.f;
    p.H1[kB * kH + b * kH + j0 + jl] = 0.f;
  }

  float* H0buf[2] = { p.H0, p.H0 + kB * kH };
  float* H1buf[2] = { p.H1, p.H1 + kB * kH };
  float c0 = 0.f, c1 = 0.f;

  grid_barrier(p.bar, bid, rnd++);

  // Generic phase: C chunks of 128 k, double-buffered staging, one sync per
  // chunk. src(c, b, k4) -> global pointer of the staged float4.
  auto runPhase = [&](int C, auto&& src, const float* const* W,
                      const float* const* Bv, int wstride, float& cs,
                      float* __restrict__ hout) {
    float acc[4][4];
    #pragma unroll
    for (int a = 0; a < 4; ++a)
      #pragma unroll
      for (int q = 0; q < 4; ++q) acc[a][q] = 0.f;

    const float* wrow[4];
    #pragma unroll
    for (int rr = 0; rr < 4; ++rr) wrow[rr] = W[r4] + (j0 + rr) * wstride;

    { // prologue: cold-stage chunk 0
      const float4 a0 = *(const float4*)src(0, bL0, k4s);
      const float4 a1 = *(const float4*)src(0, bL1, k4s);
      *(float4*)(&ustg[0][bbs0 * 132 + k4s * 4]) = a0;
      *(float4*)(&ustg[0][bbs1 * 132 + k4s * 4]) = a1;
    }
    __syncthreads();

    for (int c = 0; c < C; ++c) {
      float4 n0, n1;
      const bool more = (c + 1 < C);
      if (more) {                       // issue next-chunk loads EARLY:
        n0 = *(const float4*)src(c + 1, bL0, k4s);   // latency hides under
        n1 = *(const float4*)src(c + 1, bL1, k4s);   // this chunk's FMAs
      }
      const float* __restrict__ ub0 = ustg[c & 1];
      #pragma unroll
      for (int m = 0; m < 2; ++m) {
        const int k4 = m * 16 + kt;
        float4 wv[4], uv[4];
        #pragma unroll
        for (int rr = 0; rr < 4; ++rr)
          wv[rr] = *(const float4*)(wrow[rr] + c * 128 + k4 * 4);
        #pragma unroll
        for (int i2 = 0; i2 < 4; ++i2)
          uv[i2] = *(const float4*)(ub0 + (bg + 8 * i2) * 132 + k4 * 4);
        #pragma unroll
        for (int rr = 0; rr < 4; ++rr)
          #pragma unroll
          for (int i2 = 0; i2 < 4; ++i2) {
            acc[rr][i2] = fmaf(wv[rr].x, uv[i2].x, acc[rr][i2]);
            acc[rr][i2] = fmaf(wv[rr].y, uv[i2].y, acc[rr][i2]);
            acc[rr][i2] = fmaf(wv[rr].z, uv[i2].z, acc[rr][i2]);
            acc[rr][i2] = fmaf(wv[rr].w, uv[i2].w, acc[rr][i2]);
          }
      }
      if (more) {                       // land next chunk in the other buffer
        *(float4*)(&ustg[(c + 1) & 1][bbs0 * 132 + k4s * 4]) = n0;
        *(float4*)(&ustg[(c + 1) & 1][bbs1 * 132 + k4s * 4]) = n1;
      }
      __syncthreads();                  // one sync per chunk
    }

    // k-split reduction + bias
    #pragma unroll
    for (int rr = 0; rr < 4; ++rr)
      #pragma unroll
      for (int i2 = 0; i2 < 4; ++i2)
        part[kt * 520 + (r4 * 4 + rr) * 32 + bg + 8 * i2] = acc[rr][i2];
    __syncthreads();
    {
      const int row = tid >> 5;
      float s = 0.f;
      #pragma unroll
      for (int q = 0; q < 16; ++q) s += part[q * 520 + tid];
      s += Bv[row >> 2][j0 + (row & 3)];
      gs[tid] = s;
    }
    __syncthreads();
    if (tid < 128) {
      const int jl = tid >> 5, bb = tid & 31;
      const int b = bbase + bb;
      const float fg = sigmoidf_(gs[(0 + jl) * 32 + bb]);
      const float ig = sigmoidf_(gs[(4 + jl) * 32 + bb]);
      const float og = sigmoidf_(gs[(8 + jl) * 32 + bb]);
      const float gg = tanhf(gs[(12 + jl) * 32 + bb]);
      cs = fg * cs + ig * gg;
      hout[b * kH + j0 + jl] = og * tanhf(cs);
    }
    // no trailing sync needed: next phase's prologue sync covers ustg reuse,
    // and ustg[0] was last read before the final chunk-loop sync.
  };

  // ---------- fused sequence: 1 grid barrier per step ----------
  {
    const float* __restrict__ h0prev = H0buf[1];
    auto srcA = [&](int c, int b, int k4) {
      return (c == 0) ? p.x + (b * kS + 0) * kD + k4 * 4
                      : h0prev + b * kH + (c - 1) * 128 + k4 * 4;
    };
    runPhase(5, srcA, p.w0, p.b0, 640, c0, H0buf[0]);
  }
  grid_barrier(p.bar, bid, rnd++);

  for (int t = 0; t < kS; ++t) {
    {
      const float* __restrict__ h0cur  = H0buf[t & 1];
      const float* __restrict__ h1prev = H1buf[(t + 1) & 1];
      auto srcB = [&](int c, int b, int k4) {
        return (c < 4) ? h0cur + b * kH + c * 128 + k4 * 4
                       : h1prev + b * kH + (c - 4) * 128 + k4 * 4;
      };
      runPhase(8, srcB, p.w1, p.b1, 1024, c1, H1buf[t & 1]);
    }
    if (t < kS - 1) {
      const int tn = t + 1;
      const float* __restrict__ h0prev = H0buf[t & 1];
      auto srcA = [&](int c, int b, int k4) {
        return (c == 0) ? p.x + (b * kS + tn) * kD + k4 * 4
                        : h0prev + b * kH + (c - 1) * 128 + k4 * 4;
      };
      runPhase(5, srcA, p.w0, p.b0, 640, c0, H0buf[(t + 1) & 1]);
    }
    grid_barrier(p.bar, bid, rnd++);
  }

  // ---------- head: fc1 -> fc2 -> relu ----------
  const float* h1f = H1buf[(kS - 1) & 1];
  if (tid < 128) {
    const int jl = tid >> 5, bb = tid & 31;
    const int b = bbase + bb;
    const float* __restrict__ wr = p.fc1w + (j0 + jl) * kH;
    const float* __restrict__ hr = h1f + b * kH;
    float s = p.fc1b[j0 + jl];
    for (int k = 0; k < kH; k += 4) {
      const float4 wv = *(const float4*)(wr + k);
      const float4 hv = *(const float4*)(hr + k);
      s = fmaf(wv.x, hv.x, s); s = fmaf(wv.y, hv.y, s);
      s = fmaf(wv.z, hv.z, s); s = fmaf(wv.w, hv.w, s);
    }
    p.tmp1[b * kH + j0 + jl] = s;
  }
  grid_barrier(p.bar, bid, rnd++);
  if (bid < kOut && tid < kB) {
    const int b = tid;
    const float* __restrict__ wr = p.fc2w + bid * kH;
    const float* __restrict__ tr = p.tmp1 + b * kH;
    float s = p.fc2b[bid];
    for (int k = 0; k < kH; k += 4) {
      const float4 wv = *(const float4*)(wr + k);
      const float4 tv = *(const float4*)(tr + k);
      s = fmaf(wv.x, tv.x, s); s = fmaf(wv.y, tv.y, s);
      s = fmaf(wv.z, tv.z, s); s = fmaf(wv.w, tv.w, s);
    }
    p.out[b * kOut + bid] = fmaxf(s, 0.f);
  }
}

extern "C" void kernel_launch(void* const* d_in, const int* in_sizes, int n_in,
                              void* d_out, int out_size, void* d_ws, size_t ws_size,
                              hipStream_t stream) {
  (void)in_sizes; (void)n_in; (void)out_size; (void)ws_size;
  Params p;
  p.x = (const float*)d_in[0];
  p.w0[0] = (const float*)d_in[1];  p.b0[0] = (const float*)d_in[2];
  p.w0[1] = (const float*)d_in[3];  p.b0[1] = (const float*)d_in[4];
  p.w0[2] = (const float*)d_in[5];  p.b0[2] = (const float*)d_in[6];
  p.w0[3] = (const float*)d_in[7];  p.b0[3] = (const float*)d_in[8];
  p.w1[0] = (const float*)d_in[9];  p.b1[0] = (const float*)d_in[10];
  p.w1[1] = (const float*)d_in[11]; p.b1[1] = (const float*)d_in[12];
  p.w1[2] = (const float*)d_in[13]; p.b1[2] = (const float*)d_in[14];
  p.w1[3] = (const float*)d_in[15]; p.b1[3] = (const float*)d_in[16];
  p.fc1w = (const float*)d_in[17];  p.fc1b = (const float*)d_in[18];
  p.fc2w = (const float*)d_in[19];  p.fc2b = (const float*)d_in[20];

  float* ws = (float*)d_ws;
  p.H0   = ws;                       // 2 * 64*512
  p.H1   = ws + 2 * kB * kH;         // 2 * 64*512
  p.tmp1 = ws + 4 * kB * kH;         // 64*512
  p.bar  = (unsigned*)((char*)d_ws + kBarOffBytes);
  p.out  = (float*)d_out;

  // barrier counters must start at 0 (ws is poisoned 0xAA before every launch)
  hipMemsetAsync((char*)d_ws + kBarOffBytes, 0, 1024, stream);

  void* args[] = { &p };
  hipLaunchCooperativeKernel(reinterpret_cast<const void*>(&lstm_persistent),
                             dim3(kBlocks), dim3(kThreads), args, 0, stream);
}

// Round 2
// 21183.755 us; speedup vs baseline: 1.3002x; 1.3002x over previous
//
#include <hip/hip_runtime.h>
#include <cmath>

constexpr int kB = 64, kS = 512, kD = 128, kH = 512, kOut = 24;
constexpr int kBlocks = 256, kThreads = 512;   // grid<=256: proven coop-launchable
constexpr size_t kBarOffBytes = (size_t)5 * kB * kH * 4;   // after H0,H1,tmp1

struct Params {
  const float* x;
  const float* w0[4]; const float* b0[4];   // f,i,o,g  [512,640] / [512]
  const float* w1[4]; const float* b1[4];   // f,i,o,g  [512,1024] / [512]
  const float* fc1w; const float* fc1b;
  const float* fc2w; const float* fc2b;
  float* H0;    // 2 buffers [64][512]
  float* H1;    // 2 buffers [64][512]
  float* tmp1;  // [64][512]
  unsigned* bar; // barrier state: leaf[8] @ i*16, root @ 128, gen @ 144
  float* out;   // [64][24]
};

__device__ __forceinline__ float sigmoidf_(float v) {
  return 1.0f / (1.0f + expf(-v));
}

// Two-level monotone barrier. Leaf = bid>>5: round-1 FETCH evidence says
// adjacent bids share an L2 (contiguous-chunk dispatch), so group 32
// consecutive bids per leaf (perf-only assumption; correctness holds for any
// mapping). 32 blocks/leaf, 8 leaves -> root -> gen. Monotone counters.
__device__ __forceinline__ void grid_barrier(unsigned* bar, int bid, unsigned r) {
  __syncthreads();
  if (threadIdx.x == 0) {
    __threadfence();                                  // release
    unsigned prev = atomicAdd(&bar[(bid >> 5) * 16], 1u);
    if (prev == r * 32u + 31u) {                      // leaf winner
      __threadfence();
      unsigned rp = atomicAdd(&bar[128], 1u);
      if (rp == r * 8u + 7u) {                        // root winner
        __threadfence();
        atomicAdd(&bar[144], 1u);                     // gen = r+1
      }
    }
    while (__hip_atomic_load(&bar[144], __ATOMIC_RELAXED,
                             __HIP_MEMORY_SCOPE_AGENT) <= r) {
      __builtin_amdgcn_s_sleep(2);
    }
    __threadfence();                                  // acquire
  }
  __syncthreads();
}

// Block (cgi, bh): cgi=bid>>1 owns hidden cols j0=4*cgi..j0+3 (all 4 gates),
// bh=bid&1 owns batches bh*32..+31.  REVERTED from bid&127/bid>>7: round-1
// FETCH exploded 13x (full weight refetch every step), proving the slice-pair
// (2c,2c+1) on ADJACENT bids is what keeps per-XCD weight footprint 1.66MB
// and L2-resident. Adjacent-bids-share-L2 is the empirically supported model.
// Thread tid = r4*128 + kt*8 + bg  (r4: gate, kt: k-split, bg: batch group).
__global__ void __launch_bounds__(kThreads, 2)
lstm_persistent(Params p) {
  __shared__ float ustg[2][32 * 132];  // double-buffered u-stage (2 x 16.5KB)
  __shared__ float part[16 * 520];     // k-split partials
  __shared__ float gs[512];            // gate preactivations [row(16)][b(32)]

  const int tid = threadIdx.x;
  const int bid = blockIdx.x;
  const int cgi = bid >> 1;
  const int bh  = bid & 1;
  const int j0  = cgi * 4;
  const int bbase = bh * 32;

  const int r4 = tid >> 7;
  const int kt = (tid >> 3) & 15;
  const int bg = tid & 7;

  // staging thread map: thread loads float4 k4s of batch rows bbs0 and bbs1
  const int k4s  = tid & 31;
  const int bbs0 = tid >> 5;
  const int bbs1 = bbs0 + 16;
  const int bL0 = bbase + bbs0, bL1 = bbase + bbs1;

  unsigned rnd = 0;

  // zero-init buffers read at t=0 (buffer index 1)
  if (tid < 128) {
    const int jl = tid >> 5, bb = tid & 31;
    const int b = bbase + bb;
    p.H0[kB * kH + b * kH + j0 + jl] = 0.f;
    p.H1[kB * kH + b * kH + j0 + jl] = 0.f;
  }

  float* H0buf[2] = { p.H0, p.H0 + kB * kH };
  float* H1buf[2] = { p.H1, p.H1 + kB * kH };
  float c0 = 0.f, c1 = 0.f;

  grid_barrier(p.bar, bid, rnd++);

  // Generic phase: C chunks of 128 k, double-buffered staging, one sync per
  // chunk. src(c, b, k4) -> global pointer of the staged float4.
  auto runPhase = [&](int C, auto&& src, const float* const* W,
                      const float* const* Bv, int wstride, float& cs,
                      float* __restrict__ hout) {
    float acc[4][4];
    #pragma unroll
    for (int a = 0; a < 4; ++a)
      #pragma unroll
      for (int q = 0; q < 4; ++q) acc[a][q] = 0.f;

    const float* wrow[4];
    #pragma unroll
    for (int rr = 0; rr < 4; ++rr) wrow[rr] = W[r4] + (j0 + rr) * wstride;

    { // prologue: cold-stage chunk 0
      const float4 a0 = *(const float4*)src(0, bL0, k4s);
      const float4 a1 = *(const float4*)src(0, bL1, k4s);
      *(float4*)(&ustg[0][bbs0 * 132 + k4s * 4]) = a0;
      *(float4*)(&ustg[0][bbs1 * 132 + k4s * 4]) = a1;
    }
    __syncthreads();

    for (int c = 0; c < C; ++c) {
      float4 n0, n1;
      const bool more = (c + 1 < C);
      if (more) {                       // issue next-chunk loads EARLY:
        n0 = *(const float4*)src(c + 1, bL0, k4s);   // latency hides under
        n1 = *(const float4*)src(c + 1, bL1, k4s);   // this chunk's FMAs
      }
      const float* __restrict__ ub0 = ustg[c & 1];
      #pragma unroll
      for (int m = 0; m < 2; ++m) {
        const int k4 = m * 16 + kt;
        float4 wv[4], uv[4];
        #pragma unroll
        for (int rr = 0; rr < 4; ++rr)
          wv[rr] = *(const float4*)(wrow[rr] + c * 128 + k4 * 4);
        #pragma unroll
        for (int i2 = 0; i2 < 4; ++i2)
          uv[i2] = *(const float4*)(ub0 + (bg + 8 * i2) * 132 + k4 * 4);
        #pragma unroll
        for (int rr = 0; rr < 4; ++rr)
          #pragma unroll
          for (int i2 = 0; i2 < 4; ++i2) {
            acc[rr][i2] = fmaf(wv[rr].x, uv[i2].x, acc[rr][i2]);
            acc[rr][i2] = fmaf(wv[rr].y, uv[i2].y, acc[rr][i2]);
            acc[rr][i2] = fmaf(wv[rr].z, uv[i2].z, acc[rr][i2]);
            acc[rr][i2] = fmaf(wv[rr].w, uv[i2].w, acc[rr][i2]);
          }
      }
      if (more) {                       // land next chunk in the other buffer
        *(float4*)(&ustg[(c + 1) & 1][bbs0 * 132 + k4s * 4]) = n0;
        *(float4*)(&ustg[(c + 1) & 1][bbs1 * 132 + k4s * 4]) = n1;
      }
      __syncthreads();                  // one sync per chunk
    }

    // k-split reduction + bias
    #pragma unroll
    for (int rr = 0; rr < 4; ++rr)
      #pragma unroll
      for (int i2 = 0; i2 < 4; ++i2)
        part[kt * 520 + (r4 * 4 + rr) * 32 + bg + 8 * i2] = acc[rr][i2];
    __syncthreads();
    {
      const int row = tid >> 5;
      float s = 0.f;
      #pragma unroll
      for (int q = 0; q < 16; ++q) s += part[q * 520 + tid];
      s += Bv[row >> 2][j0 + (row & 3)];
      gs[tid] = s;
    }
    __syncthreads();
    if (tid < 128) {
      const int jl = tid >> 5, bb = tid & 31;
      const int b = bbase + bb;
      const float fg = sigmoidf_(gs[(0 + jl) * 32 + bb]);
      const float ig = sigmoidf_(gs[(4 + jl) * 32 + bb]);
      const float og = sigmoidf_(gs[(8 + jl) * 32 + bb]);
      const float gg = tanhf(gs[(12 + jl) * 32 + bb]);
      cs = fg * cs + ig * gg;
      hout[b * kH + j0 + jl] = og * tanhf(cs);
    }
    // no trailing sync needed: next phase's prologue sync covers ustg reuse,
    // and ustg buffers were last read before the final chunk-loop sync.
  };

  // ---------- fused sequence: 1 grid barrier per step ----------
  {
    const float* __restrict__ h0prev = H0buf[1];
    auto srcA = [&](int c, int b, int k4) {
      return (c == 0) ? p.x + (b * kS + 0) * kD + k4 * 4
                      : h0prev + b * kH + (c - 1) * 128 + k4 * 4;
    };
    runPhase(5, srcA, p.w0, p.b0, 640, c0, H0buf[0]);
  }
  grid_barrier(p.bar, bid, rnd++);

  for (int t = 0; t < kS; ++t) {
    {
      const float* __restrict__ h0cur  = H0buf[t & 1];
      const float* __restrict__ h1prev = H1buf[(t + 1) & 1];
      auto srcB = [&](int c, int b, int k4) {
        return (c < 4) ? h0cur + b * kH + c * 128 + k4 * 4
                       : h1prev + b * kH + (c - 4) * 128 + k4 * 4;
      };
      runPhase(8, srcB, p.w1, p.b1, 1024, c1, H1buf[t & 1]);
    }
    if (t < kS - 1) {
      const int tn = t + 1;
      const float* __restrict__ h0prev = H0buf[t & 1];
      auto srcA = [&](int c, int b, int k4) {
        return (c == 0) ? p.x + (b * kS + tn) * kD + k4 * 4
                        : h0prev + b * kH + (c - 1) * 128 + k4 * 4;
      };
      runPhase(5, srcA, p.w0, p.b0, 640, c0, H0buf[(t + 1) & 1]);
    }
    grid_barrier(p.bar, bid, rnd++);
  }

  // ---------- head: fc1 -> fc2 -> relu ----------
  const float* h1f = H1buf[(kS - 1) & 1];
  if (tid < 128) {
    const int jl = tid >> 5, bb = tid & 31;
    const int b = bbase + bb;
    const float* __restrict__ wr = p.fc1w + (j0 + jl) * kH;
    const float* __restrict__ hr = h1f + b * kH;
    float s = p.fc1b[j0 + jl];
    for (int k = 0; k < kH; k += 4) {
      const float4 wv = *(const float4*)(wr + k);
      const float4 hv = *(const float4*)(hr + k);
      s = fmaf(wv.x, hv.x, s); s = fmaf(wv.y, hv.y, s);
      s = fmaf(wv.z, hv.z, s); s = fmaf(wv.w, hv.w, s);
    }
    p.tmp1[b * kH + j0 + jl] = s;
  }
  grid_barrier(p.bar, bid, rnd++);
  if (bid < kOut && tid < kB) {
    const int b = tid;
    const float* __restrict__ wr = p.fc2w + bid * kH;
    const float* __restrict__ tr = p.tmp1 + b * kH;
    float s = p.fc2b[bid];
    for (int k = 0; k < kH; k += 4) {
      const float4 wv = *(const float4*)(wr + k);
      const float4 tv = *(const float4*)(tr + k);
      s = fmaf(wv.x, tv.x, s); s = fmaf(wv.y, tv.y, s);
      s = fmaf(wv.z, tv.z, s); s = fmaf(wv.w, tv.w, s);
    }
    p.out[b * kOut + bid] = fmaxf(s, 0.f);
  }
}

extern "C" void kernel_launch(void* const* d_in, const int* in_sizes, int n_in,
                              void* d_out, int out_size, void* d_ws, size_t ws_size,
                              hipStream_t stream) {
  (void)in_sizes; (void)n_in; (void)out_size; (void)ws_size;
  Params p;
  p.x = (const float*)d_in[0];
  p.w0[0] = (const float*)d_in[1];  p.b0[0] = (const float*)d_in[2];
  p.w0[1] = (const float*)d_in[3];  p.b0[1] = (const float*)d_in[4];
  p.w0[2] = (const float*)d_in[5];  p.b0[2] = (const float*)d_in[6];
  p.w0[3] = (const float*)d_in[7];  p.b0[3] = (const float*)d_in[8];
  p.w1[0] = (const float*)d_in[9];  p.b1[0] = (const float*)d_in[10];
  p.w1[1] = (const float*)d_in[11]; p.b1[1] = (const float*)d_in[12];
  p.w1[2] = (const float*)d_in[13]; p.b1[2] = (const float*)d_in[14];
  p.w1[3] = (const float*)d_in[15]; p.b1[3] = (const float*)d_in[16];
  p.fc1w = (const float*)d_in[17];  p.fc1b = (const float*)d_in[18];
  p.fc2w = (const float*)d_in[19];  p.fc2b = (const float*)d_in[20];

  float* ws = (float*)d_ws;
  p.H0   = ws;                       // 2 * 64*512
  p.H1   = ws + 2 * kB * kH;         // 2 * 64*512
  p.tmp1 = ws + 4 * kB * kH;         // 64*512
  p.bar  = (unsigned*)((char*)d_ws + kBarOffBytes);
  p.out  = (float*)d_out;

  // barrier counters must start at 0 (ws is poisoned 0xAA before every launch)
  hipMemsetAsync((char*)d_ws + kBarOffBytes, 0, 1024, stream);

  void* args[] = { &p };
  hipLaunchCooperativeKernel(reinterpret_cast<const void*>(&lstm_persistent),
                             dim3(kBlocks), dim3(kThreads), args, 0, stream);
}

// Round 3
// 19356.419 us; speedup vs baseline: 1.4230x; 1.0944x over previous
//
#include <hip/hip_runtime.h>
#include <cmath>

constexpr int kB = 64, kS = 512, kD = 128, kH = 512, kOut = 24;
constexpr int kBlocks = 256, kThreads = 512;   // grid<=256: proven coop-launchable
constexpr size_t kBarOffBytes = (size_t)5 * kB * kH * 4;   // after H0,H1,tmp1

struct Params {
  const float* x;
  const float* w0[4]; const float* b0[4];   // f,i,o,g  [512,640] / [512]
  const float* w1[4]; const float* b1[4];   // f,i,o,g  [512,1024] / [512]
  const float* fc1w; const float* fc1b;
  const float* fc2w; const float* fc2b;
  float* H0;    // 2 buffers [64][512]
  float* H1;    // 2 buffers [64][512]
  float* tmp1;  // [64][512]
  unsigned* bar; // layout: leafCnt[l]@l*32, rootCnt@256, rootGen@288, leafGen[l]@320+l*32
  float* out;   // [64][24]
};

__device__ __forceinline__ float sigmoidf_(float v) {
  return 1.0f / (1.0f + expf(-v));
}

// Two-level monotone barrier with LOCAL-SPIN release.
// Dispatch model (learn_hip m157, measured): XCD = bid % 8 round-robin.
//  - leaf = bid&7  -> each leaf's 32 arrival RMWs stay on ONE XCD's L2
//    (round-2 regression of +7us/step came from leaf=bid>>5 bouncing the
//    arrival line across XCDs).
//  - release: only 8 leaf winners poll rootGen cross-XCD; the other 248
//    blocks poll their XCD-local leafGen line, bumped by their leaf winner.
//    Cuts cross-XCD poll traffic on the hot release line by 32x.
// Monotone counters (target depends on round r) -> no reset race.
__device__ __forceinline__ void grid_barrier(unsigned* bar, int bid, unsigned r) {
  __syncthreads();
  if (threadIdx.x == 0) {
    const int leaf = bid & 7;
    unsigned* leafCnt = bar + leaf * 32;
    unsigned* rootCnt = bar + 256;
    unsigned* rootGen = bar + 288;
    unsigned* leafGen = bar + 320 + leaf * 32;
    __threadfence();                                  // release my writes
    unsigned prev = atomicAdd(leafCnt, 1u);
    if (prev == r * 32u + 31u) {                      // leaf winner
      __threadfence();
      unsigned rp = atomicAdd(rootCnt, 1u);
      if (rp == r * 8u + 7u) {                        // root winner
        __threadfence();
        atomicAdd(rootGen, 1u);                       // rootGen = r+1
      } else {
        while (__hip_atomic_load(rootGen, __ATOMIC_RELAXED,
                                 __HIP_MEMORY_SCOPE_AGENT) <= r) {
          __builtin_amdgcn_s_sleep(1);
        }
      }
      __threadfence();                                // chain HB through winner
      atomicAdd(leafGen, 1u);                         // XCD-local broadcast
    } else {
      while (__hip_atomic_load(leafGen, __ATOMIC_RELAXED,
                               __HIP_MEMORY_SCOPE_AGENT) <= r) {
        __builtin_amdgcn_s_sleep(1);
      }
    }
    __threadfence();                                  // acquire
  }
  __syncthreads();
}

// Block (cgi, bh): cgi=bid>>1 owns hidden cols j0=4*cgi..j0+3 (all 4 gates),
// bh=bid&1 owns batches bh*32..+31.  (Round-1's FETCH explosion is now
// attributed to VGPR-64 scratch spills from launch_bounds(,4), not the cgi
// remap; keeping the round-0 mapping which is empirically good.)
// Thread tid = r4*128 + kt*8 + bg  (r4: gate, kt: k-split, bg: batch group).
__global__ void __launch_bounds__(kThreads, 2)
lstm_persistent(Params p) {
  __shared__ float ustg[2][32 * 132];  // double-buffered u-stage (2 x 16.5KB)
  __shared__ float part[16 * 520];     // k-split partials
  __shared__ float gs[512];            // gate preactivations [row(16)][b(32)]

  const int tid = threadIdx.x;
  const int bid = blockIdx.x;
  const int cgi = bid >> 1;
  const int bh  = bid & 1;
  const int j0  = cgi * 4;
  const int bbase = bh * 32;

  const int r4 = tid >> 7;
  const int kt = (tid >> 3) & 15;
  const int bg = tid & 7;

  // staging thread map: thread loads float4 k4s of batch rows bbs0 and bbs1
  const int k4s  = tid & 31;
  const int bbs0 = tid >> 5;
  const int bbs1 = bbs0 + 16;
  const int bL0 = bbase + bbs0, bL1 = bbase + bbs1;

  unsigned rnd = 0;

  // zero-init buffers read at t=0 (buffer index 1)
  if (tid < 128) {
    const int jl = tid >> 5, bb = tid & 31;
    const int b = bbase + bb;
    p.H0[kB * kH + b * kH + j0 + jl] = 0.f;
    p.H1[kB * kH + b * kH + j0 + jl] = 0.f;
  }

  float* H0buf[2] = { p.H0, p.H0 + kB * kH };
  float* H1buf[2] = { p.H1, p.H1 + kB * kH };
  float c0 = 0.f, c1 = 0.f;

  grid_barrier(p.bar, bid, rnd++);

  // Generic phase: C chunks of 128 k, double-buffered staging, one sync per
  // chunk. src(c, b, k4) -> global pointer of the staged float4.
  auto runPhase = [&](int C, auto&& src, const float* const* W,
                      const float* const* Bv, int wstride, float& cs,
                      float* __restrict__ hout) {
    float acc[4][4];
    #pragma unroll
    for (int a = 0; a < 4; ++a)
      #pragma unroll
      for (int q = 0; q < 4; ++q) acc[a][q] = 0.f;

    const float* wrow[4];
    #pragma unroll
    for (int rr = 0; rr < 4; ++rr) wrow[rr] = W[r4] + (j0 + rr) * wstride;

    { // prologue: cold-stage chunk 0
      const float4 a0 = *(const float4*)src(0, bL0, k4s);
      const float4 a1 = *(const float4*)src(0, bL1, k4s);
      *(float4*)(&ustg[0][bbs0 * 132 + k4s * 4]) = a0;
      *(float4*)(&ustg[0][bbs1 * 132 + k4s * 4]) = a1;
    }
    __syncthreads();

    for (int c = 0; c < C; ++c) {
      float4 n0, n1;
      const bool more = (c + 1 < C);
      if (more) {                       // issue next-chunk loads EARLY:
        n0 = *(const float4*)src(c + 1, bL0, k4s);   // latency hides under
        n1 = *(const float4*)src(c + 1, bL1, k4s);   // this chunk's FMAs
      }
      const float* __restrict__ ub0 = ustg[c & 1];
      #pragma unroll
      for (int m = 0; m < 2; ++m) {
        const int k4 = m * 16 + kt;
        float4 wv[4], uv[4];
        #pragma unroll
        for (int rr = 0; rr < 4; ++rr)
          wv[rr] = *(const float4*)(wrow[rr] + c * 128 + k4 * 4);
        #pragma unroll
        for (int i2 = 0; i2 < 4; ++i2)
          uv[i2] = *(const float4*)(ub0 + (bg + 8 * i2) * 132 + k4 * 4);
        #pragma unroll
        for (int rr = 0; rr < 4; ++rr)
          #pragma unroll
          for (int i2 = 0; i2 < 4; ++i2) {
            acc[rr][i2] = fmaf(wv[rr].x, uv[i2].x, acc[rr][i2]);
            acc[rr][i2] = fmaf(wv[rr].y, uv[i2].y, acc[rr][i2]);
            acc[rr][i2] = fmaf(wv[rr].z, uv[i2].z, acc[rr][i2]);
            acc[rr][i2] = fmaf(wv[rr].w, uv[i2].w, acc[rr][i2]);
          }
      }
      if (more) {                       // land next chunk in the other buffer
        *(float4*)(&ustg[(c + 1) & 1][bbs0 * 132 + k4s * 4]) = n0;
        *(float4*)(&ustg[(c + 1) & 1][bbs1 * 132 + k4s * 4]) = n1;
      }
      __syncthreads();                  // one sync per chunk
    }

    // k-split reduction + bias
    #pragma unroll
    for (int rr = 0; rr < 4; ++rr)
      #pragma unroll
      for (int i2 = 0; i2 < 4; ++i2)
        part[kt * 520 + (r4 * 4 + rr) * 32 + bg + 8 * i2] = acc[rr][i2];
    __syncthreads();
    {
      const int row = tid >> 5;
      float s = 0.f;
      #pragma unroll
      for (int q = 0; q < 16; ++q) s += part[q * 520 + tid];
      s += Bv[row >> 2][j0 + (row & 3)];
      gs[tid] = s;
    }
    __syncthreads();
    if (tid < 128) {
      const int jl = tid >> 5, bb = tid & 31;
      const int b = bbase + bb;
      const float fg = sigmoidf_(gs[(0 + jl) * 32 + bb]);
      const float ig = sigmoidf_(gs[(4 + jl) * 32 + bb]);
      const float og = sigmoidf_(gs[(8 + jl) * 32 + bb]);
      const float gg = tanhf(gs[(12 + jl) * 32 + bb]);
      cs = fg * cs + ig * gg;
      hout[b * kH + j0 + jl] = og * tanhf(cs);
    }
    // no trailing sync needed: ustg buffers were last read before the final
    // chunk-loop sync, and gs/part reuse is covered by the gs sync above.
  };

  // ---------- fused sequence: 1 grid barrier per step ----------
  {
    const float* __restrict__ h0prev = H0buf[1];
    auto srcA = [&](int c, int b, int k4) {
      return (c == 0) ? p.x + (b * kS + 0) * kD + k4 * 4
                      : h0prev + b * kH + (c - 1) * 128 + k4 * 4;
    };
    runPhase(5, srcA, p.w0, p.b0, 640, c0, H0buf[0]);
  }
  grid_barrier(p.bar, bid, rnd++);

  for (int t = 0; t < kS; ++t) {
    {
      const float* __restrict__ h0cur  = H0buf[t & 1];
      const float* __restrict__ h1prev = H1buf[(t + 1) & 1];
      auto srcB = [&](int c, int b, int k4) {
        return (c < 4) ? h0cur + b * kH + c * 128 + k4 * 4
                       : h1prev + b * kH + (c - 4) * 128 + k4 * 4;
      };
      runPhase(8, srcB, p.w1, p.b1, 1024, c1, H1buf[t & 1]);
    }
    if (t < kS - 1) {
      const int tn = t + 1;
      const float* __restrict__ h0prev = H0buf[t & 1];
      auto srcA = [&](int c, int b, int k4) {
        return (c == 0) ? p.x + (b * kS + tn) * kD + k4 * 4
                        : h0prev + b * kH + (c - 1) * 128 + k4 * 4;
      };
      runPhase(5, srcA, p.w0, p.b0, 640, c0, H0buf[(t + 1) & 1]);
    }
    grid_barrier(p.bar, bid, rnd++);
  }

  // ---------- head: fc1 -> fc2 -> relu ----------
  const float* h1f = H1buf[(kS - 1) & 1];
  if (tid < 128) {
    const int jl = tid >> 5, bb = tid & 31;
    const int b = bbase + bb;
    const float* __restrict__ wr = p.fc1w + (j0 + jl) * kH;
    const float* __restrict__ hr = h1f + b * kH;
    float s = p.fc1b[j0 + jl];
    for (int k = 0; k < kH; k += 4) {
      const float4 wv = *(const float4*)(wr + k);
      const float4 hv = *(const float4*)(hr + k);
      s = fmaf(wv.x, hv.x, s); s = fmaf(wv.y, hv.y, s);
      s = fmaf(wv.z, hv.z, s); s = fmaf(wv.w, hv.w, s);
    }
    p.tmp1[b * kH + j0 + jl] = s;
  }
  grid_barrier(p.bar, bid, rnd++);
  if (bid < kOut && tid < kB) {
    const int b = tid;
    const float* __restrict__ wr = p.fc2w + bid * kH;
    const float* __restrict__ tr = p.tmp1 + b * kH;
    float s = p.fc2b[bid];
    for (int k = 0; k < kH; k += 4) {
      const float4 wv = *(const float4*)(wr + k);
      const float4 tv = *(const float4*)(tr + k);
      s = fmaf(wv.x, tv.x, s); s = fmaf(wv.y, tv.y, s);
      s = fmaf(wv.z, tv.z, s); s = fmaf(wv.w, tv.w, s);
    }
    p.out[b * kOut + bid] = fmaxf(s, 0.f);
  }
}

extern "C" void kernel_launch(void* const* d_in, const int* in_sizes, int n_in,
                              void* d_out, int out_size, void* d_ws, size_t ws_size,
                              hipStream_t stream) {
  (void)in_sizes; (void)n_in; (void)out_size; (void)ws_size;
  Params p;
  p.x = (const float*)d_in[0];
  p.w0[0] = (const float*)d_in[1];  p.b0[0] = (const float*)d_in[2];
  p.w0[1] = (const float*)d_in[3];  p.b0[1] = (const float*)d_in[4];
  p.w0[2] = (const float*)d_in[5];  p.b0[2] = (const float*)d_in[6];
  p.w0[3] = (const float*)d_in[7];  p.b0[3] = (const float*)d_in[8];
  p.w1[0] = (const float*)d_in[9];  p.b1[0] = (const float*)d_in[10];
  p.w1[1] = (const float*)d_in[11]; p.b1[1] = (const float*)d_in[12];
  p.w1[2] = (const float*)d_in[13]; p.b1[2] = (const float*)d_in[14];
  p.w1[3] = (const float*)d_in[15]; p.b1[3] = (const float*)d_in[16];
  p.fc1w = (const float*)d_in[17];  p.fc1b = (const float*)d_in[18];
  p.fc2w = (const float*)d_in[19];  p.fc2b = (const float*)d_in[20];

  float* ws = (float*)d_ws;
  p.H0   = ws;                       // 2 * 64*512
  p.H1   = ws + 2 * kB * kH;         // 2 * 64*512
  p.tmp1 = ws + 4 * kB * kH;         // 64*512
  p.bar  = (unsigned*)((char*)d_ws + kBarOffBytes);
  p.out  = (float*)d_out;

  // barrier counters must start at 0 (ws is poisoned 0xAA before every launch)
  // layout now spans (320 + 8*32)*4 = 2304 bytes -> clear 4KB
  hipMemsetAsync((char*)d_ws + kBarOffBytes, 0, 4096, stream);

  void* args[] = { &p };
  hipLaunchCooperativeKernel(reinterpret_cast<const void*>(&lstm_persistent),
                             dim3(kBlocks), dim3(kThreads), args, 0, stream);
}

// Round 4
// 14273.686 us; speedup vs baseline: 1.9297x; 1.3561x over previous
//
#include <hip/hip_runtime.h>
#include <cmath>

constexpr int kB = 64, kS = 512, kD = 128, kH = 512, kOut = 24;
constexpr int kBlocks = 256, kThreads = 512;   // grid<=256: proven coop-launchable
constexpr size_t kBarOffBytes = (size_t)5 * kB * kH * 4;   // after H0,H1,tmp1

struct Params {
  const float* x;
  const float* w0[4]; const float* b0[4];   // f,i,o,g  [512,640] / [512]
  const float* w1[4]; const float* b1[4];   // f,i,o,g  [512,1024] / [512]
  const float* fc1w; const float* fc1b;
  const float* fc2w; const float* fc2b;
  float* H0;    // 2 buffers [64][512]
  float* H1;    // 2 buffers [64][512]
  float* tmp1;  // [64][512]
  unsigned* bar; // word layout: dom slots [0,4096), dom gen @4096+d*16,
                 //              full slots [4224,8320), full gen @8320
  float* out;   // [64][24]
};

__device__ __forceinline__ float sigmoidf_(float v) {
  return 1.0f / (1.0f + expf(-v));
}

// Store-based group barrier (no atomic RMW serialization — round-2/3 evidence
// showed serialized same-line RMW arrival costs multiple us/step).
// Every member block STORES round r+1 into its own 64B-spaced slot (parallel).
// The leader block polls all n slots with n lanes + __syncthreads_and, then
// stores gen=r+1; non-leaders poll gen. Monotone counters, no reset race.
// Fence discipline: writer fence -> slot store; observer fence after load ->
// __syncthreads edge distributes acquire to the whole block (same pattern as
// rounds 0-3, harness-verified).
__device__ __forceinline__ void sync_group(unsigned* slots, unsigned* gen,
                                           int myIdx, int n, bool leader,
                                           unsigned r) {
  const int tid = threadIdx.x;
  __syncthreads();
  if (leader) {
    if (tid == 0) {
      __threadfence();
      __hip_atomic_store(slots + myIdx * 16, r + 1, __ATOMIC_RELAXED,
                         __HIP_MEMORY_SCOPE_AGENT);
    }
    unsigned* ps = slots + (tid < n ? tid : 0) * 16;
    for (;;) {
      unsigned v = __hip_atomic_load(ps, __ATOMIC_RELAXED,
                                     __HIP_MEMORY_SCOPE_AGENT);
      if (__syncthreads_and((tid < n) ? (int)(v > r) : 1)) break;
      __builtin_amdgcn_s_sleep(1);
    }
    __threadfence();
    if (tid == 0)
      __hip_atomic_store(gen, r + 1, __ATOMIC_RELAXED,
                         __HIP_MEMORY_SCOPE_AGENT);
    __syncthreads();
  } else {
    if (tid == 0) {
      __threadfence();
      __hip_atomic_store(slots + myIdx * 16, r + 1, __ATOMIC_RELAXED,
                         __HIP_MEMORY_SCOPE_AGENT);
      while (__hip_atomic_load(gen, __ATOMIC_RELAXED,
                               __HIP_MEMORY_SCOPE_AGENT) <= r)
        __builtin_amdgcn_s_sleep(1);
      __threadfence();
    }
    __syncthreads();
  }
}

// Block (cgi, bh): cgi=bid>>1 owns hidden cols j0=4*cgi..j0+3 (all 4 gates),
// bh=bid&1 owns batches bh*32..+31.
// DOMAINS: bh=0 and bh=1 halves never exchange data until fc2 -> two
// independent 128-block barriers per step; one full 256-block barrier pre-fc2.
// Thread tid = r4*128 + kt*8 + bg  (r4: gate, kt: k-split, bg: batch group).
__global__ void __launch_bounds__(kThreads, 2)
lstm_persistent(Params p) {
  __shared__ float wlds0[16 * 640];    // 40.0 KB: block's w0 slice (LDS-resident)
  __shared__ float wlds1[16 * 1024];   // 64.0 KB: block's w1 slice
  __shared__ float ustg[2][32 * 132];  // 33.0 KB: dbuf u-stage (part unions here)
  __shared__ float gs[512];            // gate preactivations [row(16)][b(32)]

  const int tid = threadIdx.x;
  const int bid = blockIdx.x;
  const int cgi = bid >> 1;
  const int bh  = bid & 1;
  const int j0  = cgi * 4;
  const int bbase = bh * 32;

  const int r4 = tid >> 7;
  const int kt = (tid >> 3) & 15;
  const int bg = tid & 7;

  // staging thread map: thread loads float4 k4s of batch rows bbs0 and bbs1
  const int k4s  = tid & 31;
  const int bbs0 = tid >> 5;
  const int bbs1 = bbs0 + 16;
  const int bL0 = bbase + bbs0, bL1 = bbase + bbs1;

  unsigned rnd = 0;

  // ---- one-time: weight slice -> LDS (removes per-step L2 latency+BW from
  //      the serial chunk chain; 104 global loads/thread/step become ds_reads)
  for (int idx = tid; idx < 16 * 160; idx += kThreads) {   // w0: 16 x 160 f4
    const int row = idx / 160;
    const int k4  = idx - row * 160;
    const float4 v =
        *(const float4*)(p.w0[row >> 2] + (j0 + (row & 3)) * 640 + k4 * 4);
    *(float4*)(wlds0 + row * 640 + k4 * 4) = v;
  }
  for (int idx = tid; idx < 16 * 256; idx += kThreads) {   // w1: 16 x 256 f4
    const int row = idx >> 8;
    const int k4  = idx & 255;
    const float4 v =
        *(const float4*)(p.w1[row >> 2] + (j0 + (row & 3)) * 1024 + k4 * 4);
    *(float4*)(wlds1 + row * 1024 + k4 * 4) = v;
  }

  // zero-init buffers read at t=0 (buffer index 1)
  if (tid < 128) {
    const int jl = tid >> 5, bb = tid & 31;
    const int b = bbase + bb;
    p.H0[kB * kH + b * kH + j0 + jl] = 0.f;
    p.H1[kB * kH + b * kH + j0 + jl] = 0.f;
  }

  float* H0buf[2] = { p.H0, p.H0 + kB * kH };
  float* H1buf[2] = { p.H1, p.H1 + kB * kH };
  float c0 = 0.f, c1 = 0.f;

  unsigned* domSlots = p.bar + bh * 2048;
  unsigned* domGen   = p.bar + 4096 + bh * 16;
  const bool leader  = (cgi == 0);

  sync_group(domSlots, domGen, cgi, 128, leader, rnd); rnd++;

  // Generic phase: C chunks of 128 k. Weights from LDS; u staged through a
  // 2-buffer LDS pipeline with TWO-chunk-ahead register prefetch (statically
  // named sets A/B, unroll-by-2 — runtime-indexed reg arrays would spill).
  auto runPhase = [&](int C, auto&& src, const float* __restrict__ wl,
                      int wstride, const float* const* Bv, float& cs,
                      float* __restrict__ hout) {
    float acc[4][4];
    #pragma unroll
    for (int a = 0; a < 4; ++a)
      #pragma unroll
      for (int q = 0; q < 4; ++q) acc[a][q] = 0.f;

    const float* wr[4];
    #pragma unroll
    for (int rr = 0; rr < 4; ++rr) wr[rr] = wl + (r4 * 4 + rr) * wstride;

    auto compute = [&](int c, const float* __restrict__ ub0) {
      #pragma unroll
      for (int m = 0; m < 2; ++m) {
        const int k4 = m * 16 + kt;
        float4 wv[4], uv[4];
        #pragma unroll
        for (int rr = 0; rr < 4; ++rr)
          wv[rr] = *(const float4*)(wr[rr] + c * 128 + k4 * 4);   // LDS, bcast
        #pragma unroll
        for (int i2 = 0; i2 < 4; ++i2)
          uv[i2] = *(const float4*)(ub0 + (bg + 8 * i2) * 132 + k4 * 4);
        #pragma unroll
        for (int rr = 0; rr < 4; ++rr)
          #pragma unroll
          for (int i2 = 0; i2 < 4; ++i2) {
            acc[rr][i2] = fmaf(wv[rr].x, uv[i2].x, acc[rr][i2]);
            acc[rr][i2] = fmaf(wv[rr].y, uv[i2].y, acc[rr][i2]);
            acc[rr][i2] = fmaf(wv[rr].z, uv[i2].z, acc[rr][i2]);
            acc[rr][i2] = fmaf(wv[rr].w, uv[i2].w, acc[rr][i2]);
          }
      }
    };

    // set A holds even chunks, set B odd chunks
    float4 sA0, sA1, sB0, sB1;
    sA0 = *(const float4*)src(0, bL0, k4s);
    sA1 = *(const float4*)src(0, bL1, k4s);
    if (C > 1) {
      sB0 = *(const float4*)src(1, bL0, k4s);
      sB1 = *(const float4*)src(1, bL1, k4s);
    }
    *(float4*)(&ustg[0][bbs0 * 132 + k4s * 4]) = sA0;
    *(float4*)(&ustg[0][bbs1 * 132 + k4s * 4]) = sA1;
    __syncthreads();

    for (int cc = 0; cc < C; cc += 2) {
      { // even chunk c = cc, data in LDS0
        const int c = cc;
        if (c + 2 < C) {               // issue c+2 loads: ~2-chunk window
          sA0 = *(const float4*)src(c + 2, bL0, k4s);
          sA1 = *(const float4*)src(c + 2, bL1, k4s);
        }
        compute(c, ustg[0]);
        if (c + 1 < C) {
          *(float4*)(&ustg[1][bbs0 * 132 + k4s * 4]) = sB0;
          *(float4*)(&ustg[1][bbs1 * 132 + k4s * 4]) = sB1;
        }
        __syncthreads();
      }
      if (cc + 1 < C) {                // odd chunk c = cc+1, data in LDS1
        const int c = cc + 1;
        if (c + 2 < C) {
          sB0 = *(const float4*)src(c + 2, bL0, k4s);
          sB1 = *(const float4*)src(c + 2, bL1, k4s);
        }
        compute(c, ustg[1]);
        if (c + 1 < C) {
          *(float4*)(&ustg[0][bbs0 * 132 + k4s * 4]) = sA0;
          *(float4*)(&ustg[0][bbs1 * 132 + k4s * 4]) = sA1;
        }
        __syncthreads();
      }
    }

    // k-split reduction + bias (part unions onto ustg — all chunk reads done)
    float* part = &ustg[0][0];
    #pragma unroll
    for (int rr = 0; rr < 4; ++rr)
      #pragma unroll
      for (int i2 = 0; i2 < 4; ++i2)
        part[kt * 520 + (r4 * 4 + rr) * 32 + bg + 8 * i2] = acc[rr][i2];
    __syncthreads();
    {
      const int row = tid >> 5;
      float s = 0.f;
      #pragma unroll
      for (int q = 0; q < 16; ++q) s += part[q * 520 + tid];
      s += Bv[row >> 2][j0 + (row & 3)];
      gs[tid] = s;
    }
    __syncthreads();
    if (tid < 128) {
      const int jl = tid >> 5, bb = tid & 31;
      const int b = bbase + bb;
      const float fg = sigmoidf_(gs[(0 + jl) * 32 + bb]);
      const float ig = sigmoidf_(gs[(4 + jl) * 32 + bb]);
      const float og = sigmoidf_(gs[(8 + jl) * 32 + bb]);
      const float gg = tanhf(gs[(12 + jl) * 32 + bb]);
      cs = fg * cs + ig * gg;
      hout[b * kH + j0 + jl] = og * tanhf(cs);
    }
    // part reads finished before the gs sync; next prologue may overwrite ustg
  };

  // ---------- fused sequence: 1 domain barrier per step ----------
  {
    const float* __restrict__ h0prev = H0buf[1];
    auto srcA = [&](int c, int b, int k4) {
      return (c == 0) ? p.x + (b * kS + 0) * kD + k4 * 4
                      : h0prev + b * kH + (c - 1) * 128 + k4 * 4;
    };
    runPhase(5, srcA, wlds0, 640, p.b0, c0, H0buf[0]);
  }
  sync_group(domSlots, domGen, cgi, 128, leader, rnd); rnd++;

  for (int t = 0; t < kS; ++t) {
    {
      const float* __restrict__ h0cur  = H0buf[t & 1];
      const float* __restrict__ h1prev = H1buf[(t + 1) & 1];
      auto srcB = [&](int c, int b, int k4) {
        return (c < 4) ? h0cur + b * kH + c * 128 + k4 * 4
                       : h1prev + b * kH + (c - 4) * 128 + k4 * 4;
      };
      runPhase(8, srcB, wlds1, 1024, p.b1, c1, H1buf[t & 1]);
    }
    if (t < kS - 1) {
      const int tn = t + 1;
      const float* __restrict__ h0prev = H0buf[t & 1];
      auto srcA = [&](int c, int b, int k4) {
        return (c == 0) ? p.x + (b * kS + tn) * kD + k4 * 4
                        : h0prev + b * kH + (c - 1) * 128 + k4 * 4;
      };
      runPhase(5, srcA, wlds0, 640, p.b0, c0, H0buf[(t + 1) & 1]);
    }
    sync_group(domSlots, domGen, cgi, 128, leader, rnd); rnd++;
  }

  // ---------- head: fc1 -> (FULL barrier) -> fc2 -> relu ----------
  const float* h1f = H1buf[(kS - 1) & 1];
  if (tid < 128) {
    const int jl = tid >> 5, bb = tid & 31;
    const int b = bbase + bb;
    const float* __restrict__ wrr = p.fc1w + (j0 + jl) * kH;
    const float* __restrict__ hr = h1f + b * kH;
    float s = p.fc1b[j0 + jl];
    for (int k = 0; k < kH; k += 4) {
      const float4 wv = *(const float4*)(wrr + k);
      const float4 hv = *(const float4*)(hr + k);
      s = fmaf(wv.x, hv.x, s); s = fmaf(wv.y, hv.y, s);
      s = fmaf(wv.z, hv.z, s); s = fmaf(wv.w, hv.w, s);
    }
    p.tmp1[b * kH + j0 + jl] = s;
  }
  // fc2 reads tmp1 across BOTH domains -> one full-grid barrier
  sync_group(p.bar + 4224, p.bar + 8320, bid, 256, bid == 0, 0u);

  if (bid < kOut && tid < kB) {
    const int b = tid;
    const float* __restrict__ wrr = p.fc2w + bid * kH;
    const float* __restrict__ tr = p.tmp1 + b * kH;
    float s = p.fc2b[bid];
    for (int k = 0; k < kH; k += 4) {
      const float4 wv = *(const float4*)(wrr + k);
      const float4 tv = *(const float4*)(tr + k);
      s = fmaf(wv.x, tv.x, s); s = fmaf(wv.y, tv.y, s);
      s = fmaf(wv.z, tv.z, s); s = fmaf(wv.w, tv.w, s);
    }
    p.out[b * kOut + bid] = fmaxf(s, 0.f);
  }
}

extern "C" void kernel_launch(void* const* d_in, const int* in_sizes, int n_in,
                              void* d_out, int out_size, void* d_ws, size_t ws_size,
                              hipStream_t stream) {
  (void)in_sizes; (void)n_in; (void)out_size; (void)ws_size;
  Params p;
  p.x = (const float*)d_in[0];
  p.w0[0] = (const float*)d_in[1];  p.b0[0] = (const float*)d_in[2];
  p.w0[1] = (const float*)d_in[3];  p.b0[1] = (const float*)d_in[4];
  p.w0[2] = (const float*)d_in[5];  p.b0[2] = (const float*)d_in[6];
  p.w0[3] = (const float*)d_in[7];  p.b0[3] = (const float*)d_in[8];
  p.w1[0] = (const float*)d_in[9];  p.b1[0] = (const float*)d_in[10];
  p.w1[1] = (const float*)d_in[11]; p.b1[1] = (const float*)d_in[12];
  p.w1[2] = (const float*)d_in[13]; p.b1[2] = (const float*)d_in[14];
  p.w1[3] = (const float*)d_in[15]; p.b1[3] = (const float*)d_in[16];
  p.fc1w = (const float*)d_in[17];  p.fc1b = (const float*)d_in[18];
  p.fc2w = (const float*)d_in[19];  p.fc2b = (const float*)d_in[20];

  float* ws = (float*)d_ws;
  p.H0   = ws;                       // 2 * 64*512
  p.H1   = ws + 2 * kB * kH;         // 2 * 64*512
  p.tmp1 = ws + 4 * kB * kH;         // 64*512
  p.bar  = (unsigned*)((char*)d_ws + kBarOffBytes);
  p.out  = (float*)d_out;

  // barrier state must start at 0 (ws is poisoned 0xAA before every launch)
  // region spans 8321 words -> clear 36 KB
  hipMemsetAsync((char*)d_ws + kBarOffBytes, 0, 36864, stream);

  void* args[] = { &p };
  hipLaunchCooperativeKernel(reinterpret_cast<const void*>(&lstm_persistent),
                             dim3(kBlocks), dim3(kThreads), args, 0, stream);
}